// Round 3
// baseline (256.653 us; speedup 1.0000x reference)
//
#include <hip/hip_runtime.h>
#include <stdint.h>

#define Mdim 4096
#define Kdim 4096
#define Ndim 4096

typedef __attribute__((ext_vector_type(8))) short bf16x8;   // 8 bf16 (MFMA A/B frag)
typedef __attribute__((ext_vector_type(4))) float f32x4;    // MFMA C/D frag

static __device__ __forceinline__ unsigned short f2bf_rne(float f) {
    union { float f; unsigned u; } v; v.f = f;
    unsigned u = v.u;
    u += 0x7FFFu + ((u >> 16) & 1u);
    return (unsigned short)(u >> 16);
}

static __device__ __forceinline__ void gload_lds16(const unsigned short* g, unsigned short* l) {
    __builtin_amdgcn_global_load_lds(
        (const __attribute__((address_space(1))) unsigned int*)g,
        (__attribute__((address_space(3))) unsigned int*)l,
        16, 0, 0);
}

#define BAR()  do { asm volatile("" ::: "memory"); __builtin_amdgcn_s_barrier(); asm volatile("" ::: "memory"); } while (0)
#define VMC(N) asm volatile("s_waitcnt vmcnt(" #N ")" ::: "memory")

// ---------------------------------------------------------------------------
// Conversion kernels: f32 -> bf16 (A linear, B transposed so GEMM sees B^T)
// ---------------------------------------------------------------------------
__global__ void conv_a(const float* __restrict__ a, unsigned short* __restrict__ out) {
    size_t idx = (size_t)blockIdx.x * blockDim.x + threadIdx.x;
    float4 v = ((const float4*)a)[idx];
    ushort4 o;
    o.x = f2bf_rne(v.x); o.y = f2bf_rne(v.y); o.z = f2bf_rne(v.z); o.w = f2bf_rne(v.w);
    ((ushort4*)out)[idx] = o;
}

__global__ void conv_bt(const float* __restrict__ b, unsigned short* __restrict__ bt) {
    __shared__ float tile[64][65];
    const int tn = blockIdx.x, tk = blockIdx.y;
    for (int i = threadIdx.x; i < 64 * 64; i += 256) {
        int r = i >> 6, c = i & 63;
        tile[r][c] = b[(size_t)(tk * 64 + r) * Ndim + tn * 64 + c];
    }
    __syncthreads();
    for (int i = threadIdx.x; i < 64 * 64; i += 256) {
        int n = i >> 6, k = i & 63;
        bt[(size_t)(tn * 64 + n) * Kdim + tk * 64 + k] = f2bf_rne(tile[k][n]);
    }
}

// ---------------------------------------------------------------------------
// 256x256 bf16 GEMM, register-pipelined 4-phase schedule (2 tiles unrolled).
// 512 thr = 8 waves (2M x 4N); per-wave 128x64 out = acc[8][4]. BK=64, dbuf LDS.
//
// Phase p of tile tau (buf b = tau&1):
//   ph1: ds_read bE<-B0[tau], bO<-B1[tau] | (no stage)        | MFMA Q1(aE,bE)  | VMC(8)
//   ph2: ds_read aO<-A1[tau]              | stage A0[tau+2]   | MFMA Q2(aE,bO)  | VMC(8)
//   ph3: ds_read aE<-A0[tau+1]            | stage B0,B1[tau+2]| MFMA Q3(aO,bO)  | -
//   ph4: (no reads)                       | stage A1[tau+2]   | MFMA Q4(aO,bE)  | VMC(10)
// Each phase: [reads; stage; barrier; (compiler counted lgkmcnt); setprio+MFMA;
// VMC(k); barrier]. Reads are consumed one phase later -> LDS latency hides
// under MFMA; counted vmcnt retires exactly the pair the next phase reads;
// every stage lands one barrier after forced-completion of the reads it
// overwrites (verified per-region: A0 safe>=ph2, A1>=ph4, B0>=ph2, B1>=ph3).
// ---------------------------------------------------------------------------
__global__ __launch_bounds__(512, 2) void gemm8p2(const unsigned short* __restrict__ A,
                                                  const unsigned short* __restrict__ Bt,
                                                  float* __restrict__ C) {
    __shared__ unsigned short lds[8 * 8192];  // [buf][A0,A1,B0,B1][128*64] = 128 KiB

    const int tid  = threadIdx.x;
    const int lane = tid & 63;
    const int w    = tid >> 6;
    const int wm   = w >> 2;
    const int wn   = w & 3;

    // bijective XCD swizzle (gridDim.x = 256)
    const int nchunk = gridDim.x >> 3;
    const int orig   = blockIdx.x;
    const int swz    = (orig & 7) * nchunk + (orig >> 3);
    const int bm     = swz >> 4;
    const int bn     = swz & 15;

    // ---- staging geometry (unchanged from round 2; conflict-free verified) ----
    const int pr0 = w * 8 + (lane >> 3);
    const int c0  = ((lane & 7) ^ (pr0 & 7)) * 8;    // pre-swizzled source chunk
    const int pr1 = 64 + pr0;
    const int rA0 = ((pr0 >> 6) << 7) | (pr0 & 63);
    const int rA1 = ((pr1 >> 6) << 7) | (pr1 & 63);
    const int rB0 = ((pr0 >> 5) << 6) | (pr0 & 31);
    const int rB1 = ((pr1 >> 5) << 6) | (pr1 & 31);

    const unsigned short* gA0 = A  + ((size_t)(bm * 256 + rA0) << 12) + c0;
    const unsigned short* gA1 = A  + ((size_t)(bm * 256 + rA1) << 12) + c0;
    const unsigned short* gB0 = Bt + ((size_t)(bn * 256 + rB0) << 12) + c0;
    const unsigned short* gB1 = Bt + ((size_t)(bn * 256 + rB1) << 12) + c0;

    unsigned short* ldsw = lds + w * 512;

#define STAGE_A(BUF, H, T) do {                                                           \
        gload_lds16(gA0 + (H) * (64 * 4096) + (T) * 64, ldsw + ((BUF) * 4 + (H)) * 8192); \
        gload_lds16(gA1 + (H) * (64 * 4096) + (T) * 64,                                   \
                    ldsw + ((BUF) * 4 + (H)) * 8192 + 4096);                              \
    } while (0)
#define STAGE_B(BUF, H, T) do {                                                               \
        gload_lds16(gB0 + (H) * (32 * 4096) + (T) * 64, ldsw + ((BUF) * 4 + 2 + (H)) * 8192); \
        gload_lds16(gB1 + (H) * (32 * 4096) + (T) * 64,                                       \
                    ldsw + ((BUF) * 4 + 2 + (H)) * 8192 + 4096);                              \
    } while (0)

    // ---- fragment read bases: (buf, kk) -> byte offset; reads are base+imm ----
    const int fr = lane & 15;
    const int hi = lane >> 4;
    const int sx = fr & 7;
    const char* ldsc = (const char*)lds;

    const int adA00 = 0 * 65536 + (wm * 64 + fr) * 128 + (((0 * 4 + hi) ^ sx) << 4);
    const int adA01 = 0 * 65536 + (wm * 64 + fr) * 128 + (((1 * 4 + hi) ^ sx) << 4);
    const int adA10 = 1 * 65536 + (wm * 64 + fr) * 128 + (((0 * 4 + hi) ^ sx) << 4);
    const int adA11 = 1 * 65536 + (wm * 64 + fr) * 128 + (((1 * 4 + hi) ^ sx) << 4);
    const int adB00 = 0 * 65536 + 32768 + (wn * 32 + fr) * 128 + (((0 * 4 + hi) ^ sx) << 4);
    const int adB01 = 0 * 65536 + 32768 + (wn * 32 + fr) * 128 + (((1 * 4 + hi) ^ sx) << 4);
    const int adB10 = 1 * 65536 + 32768 + (wn * 32 + fr) * 128 + (((0 * 4 + hi) ^ sx) << 4);
    const int adB11 = 1 * 65536 + 32768 + (wn * 32 + fr) * 128 + (((1 * 4 + hi) ^ sx) << 4);

#define LDA8(DST, B, MH) do { _Pragma("unroll")                                       \
        for (int m_ = 0; m_ < 4; ++m_) {                                              \
            DST[m_][0] = *(const bf16x8*)(ldsc + adA##B##0 + (MH)*16384 + m_*2048);   \
            DST[m_][1] = *(const bf16x8*)(ldsc + adA##B##1 + (MH)*16384 + m_*2048);   \
        } } while (0)
#define LDB4(DST, B, NH) do { _Pragma("unroll")                                       \
        for (int n_ = 0; n_ < 2; ++n_) {                                              \
            DST[n_][0] = *(const bf16x8*)(ldsc + adB##B##0 + (NH)*16384 + n_*2048);   \
            DST[n_][1] = *(const bf16x8*)(ldsc + adB##B##1 + (NH)*16384 + n_*2048);   \
        } } while (0)

#define MMA_QUAD(MH, NH, AF, BF) do {                                                 \
        __builtin_amdgcn_s_setprio(1);                                                \
        _Pragma("unroll")                                                             \
        for (int m_ = 0; m_ < 4; ++m_)                                                \
            _Pragma("unroll")                                                         \
            for (int n_ = 0; n_ < 2; ++n_) {                                          \
                acc[(MH)*4 + m_][(NH)*2 + n_] = __builtin_amdgcn_mfma_f32_16x16x32_bf16( \
                    AF[m_][0], BF[n_][0], acc[(MH)*4 + m_][(NH)*2 + n_], 0, 0, 0);    \
                acc[(MH)*4 + m_][(NH)*2 + n_] = __builtin_amdgcn_mfma_f32_16x16x32_bf16( \
                    AF[m_][1], BF[n_][1], acc[(MH)*4 + m_][(NH)*2 + n_], 0, 0, 0);    \
            }                                                                         \
        __builtin_amdgcn_s_setprio(0);                                                \
    } while (0)

    f32x4 acc[8][4] = {};
    bf16x8 aE[4][2], aO[4][2], bE[2][2], bO[2][2];

    // ---- prologue: stage tiles 0,1 in steady-state order; pre-read aE=A0[0] ----
    STAGE_A(0, 0, 0);                       // A0[0]
    STAGE_B(0, 0, 0); STAGE_B(0, 1, 0);     // B0[0], B1[0]
    STAGE_A(0, 1, 0);                       // A1[0]
    STAGE_A(1, 0, 1);                       // A0[1]
    STAGE_B(1, 0, 1); STAGE_B(1, 1, 1);     // B0[1], B1[1]
    STAGE_A(1, 1, 1);                       // A1[1]
    VMC(14);                                // retire A0[0]
    BAR();
    LDA8(aE, 0, 0);                         // aE <- A0[0]
    VMC(10);                                // retire B0[0], B1[0]
    BAR();

    // ---- main loop: tiles t (buf0), t+1 (buf1); t = 0,2,...,60 ----
    for (int i = 0; i < 31; ++i) {
        const int t = 2 * i;
        // ======== tile t (buf 0) ========
        // ph1
        LDB4(bE, 0, 0); LDB4(bO, 0, 1);
        BAR();
        MMA_QUAD(0, 0, aE, bE);
        VMC(8); BAR();
        // ph2
        LDA8(aO, 0, 1);
        STAGE_A(0, 0, t + 2);
        BAR();
        MMA_QUAD(0, 1, aE, bO);
        VMC(8); BAR();
        // ph3
        LDA8(aE, 1, 0);                     // A0[t+1] (buf1)
        STAGE_B(0, 0, t + 2); STAGE_B(0, 1, t + 2);
        BAR();
        MMA_QUAD(1, 1, aO, bO);
        BAR();
        // ph4
        STAGE_A(0, 1, t + 2);
        BAR();
        MMA_QUAD(1, 0, aO, bE);
        VMC(10); BAR();
        // ======== tile t+1 (buf 1) ========
        // ph1
        LDB4(bE, 1, 0); LDB4(bO, 1, 1);
        BAR();
        MMA_QUAD(0, 0, aE, bE);
        VMC(8); BAR();
        // ph2
        LDA8(aO, 1, 1);
        STAGE_A(1, 0, t + 3);
        BAR();
        MMA_QUAD(0, 1, aE, bO);
        VMC(8); BAR();
        // ph3
        LDA8(aE, 0, 0);                     // A0[t+2] (buf0)
        STAGE_B(1, 0, t + 3); STAGE_B(1, 1, t + 3);
        BAR();
        MMA_QUAD(1, 1, aO, bO);
        BAR();
        // ph4
        STAGE_A(1, 1, t + 3);
        BAR();
        MMA_QUAD(1, 0, aO, bE);
        VMC(10); BAR();
    }

    // ---- epilogue: tiles 62 (buf0), 63 (buf1) — no stages, drain once ----
    VMC(0); BAR();
    // tile 62
    LDB4(bE, 0, 0); LDB4(bO, 0, 1);
    MMA_QUAD(0, 0, aE, bE);
    LDA8(aO, 0, 1);
    MMA_QUAD(0, 1, aE, bO);
    LDA8(aE, 1, 0);                         // A0[63]
    MMA_QUAD(1, 1, aO, bO);
    MMA_QUAD(1, 0, aO, bE);
    // tile 63
    LDB4(bE, 1, 0); LDB4(bO, 1, 1);
    MMA_QUAD(0, 0, aE, bE);
    LDA8(aO, 1, 1);
    MMA_QUAD(0, 1, aE, bO);
    MMA_QUAD(1, 1, aO, bO);
    MMA_QUAD(1, 0, aO, bE);

    // ---- C write: row = (lane>>4)*4 + reg, col = lane&15 per 16x16 frag ----
    const size_t crow = (size_t)(bm * 256 + wm * 128 + hi * 4);
    const int    ccol = bn * 256 + wn * 64 + fr;
#pragma unroll
    for (int mi = 0; mi < 8; ++mi)
#pragma unroll
        for (int ni = 0; ni < 4; ++ni) {
            const size_t row = crow + mi * 16;
            const int    col = ccol + ni * 16;
#pragma unroll
            for (int r = 0; r < 4; ++r)
                C[(row + r) * Ndim + col] = acc[mi][ni][r];
        }

#undef STAGE_A
#undef STAGE_B
#undef LDA8
#undef LDB4
#undef MMA_QUAD
}

// ---------------------------------------------------------------------------
// Fallback if workspace too small: plain f32 tiles
// ---------------------------------------------------------------------------
__global__ void gemm_f32_naive(const float* __restrict__ A, const float* __restrict__ B,
                               float* __restrict__ C) {
    __shared__ float As[32][33], Bs[32][33];
    const int tx = threadIdx.x & 31, ty = threadIdx.x >> 5;
    const int row0 = blockIdx.y * 32, col0 = blockIdx.x * 32;
    float acc[4] = {0.f, 0.f, 0.f, 0.f};
    for (int k0 = 0; k0 < Kdim; k0 += 32) {
        for (int i = threadIdx.x; i < 32 * 32; i += 256) {
            int r = i >> 5, c = i & 31;
            As[r][c] = A[(size_t)(row0 + r) * Kdim + k0 + c];
            Bs[r][c] = B[(size_t)(k0 + r) * Ndim + col0 + c];
        }
        __syncthreads();
#pragma unroll 8
        for (int kk = 0; kk < 32; ++kk) {
            float bv = Bs[kk][tx];
#pragma unroll
            for (int i = 0; i < 4; ++i) acc[i] += As[ty + 8 * i][kk] * bv;
        }
        __syncthreads();
    }
#pragma unroll
    for (int i = 0; i < 4; ++i)
        C[(size_t)(row0 + ty + 8 * i) * Ndim + col0 + tx] = acc[i];
}

extern "C" void kernel_launch(void* const* d_in, const int* in_sizes, int n_in,
                              void* d_out, int out_size, void* d_ws, size_t ws_size,
                              hipStream_t stream) {
    const float* x = (const float*)d_in[0];
    const float* y = (const float*)d_in[1];
    float* out = (float*)d_out;

    const size_t elemsA = (size_t)Mdim * Kdim;
    const size_t elemsB = (size_t)Ndim * Kdim;
    const size_t need   = (elemsA + elemsB) * sizeof(unsigned short);  // 64 MiB

    if (ws_size >= need) {
        unsigned short* Abf = (unsigned short*)d_ws;
        unsigned short* Btb = Abf + elemsA;

        conv_a<<<(unsigned)(elemsA / 4 / 256), 256, 0, stream>>>(x, Abf);
        conv_bt<<<dim3(Ndim / 64, Kdim / 64), 256, 0, stream>>>(y, Btb);
        gemm8p2<<<dim3((Mdim / 256) * (Ndim / 256)), 512, 0, stream>>>(Abf, Btb, out);
    } else {
        gemm_f32_naive<<<dim3(Ndim / 32, Mdim / 32), 256, 0, stream>>>(x, y, out);
    }
}

// Round 4
// 167.959 us; speedup vs baseline: 1.5281x; 1.5281x over previous
//
#include <hip/hip_runtime.h>
#include <stdint.h>

#define Mdim 4096
#define Kdim 4096
#define Ndim 4096

typedef __attribute__((ext_vector_type(8))) short bf16x8;   // 8 bf16 (MFMA A/B frag)
typedef __attribute__((ext_vector_type(4))) float f32x4;    // MFMA C/D frag

static __device__ __forceinline__ unsigned short f2bf_rne(float f) {
    union { float f; unsigned u; } v; v.f = f;
    unsigned u = v.u;
    u += 0x7FFFu + ((u >> 16) & 1u);
    return (unsigned short)(u >> 16);
}

static __device__ __forceinline__ void gload_lds16(const unsigned short* g, unsigned short* l) {
    __builtin_amdgcn_global_load_lds(
        (const __attribute__((address_space(1))) unsigned int*)g,
        (__attribute__((address_space(3))) unsigned int*)l,
        16, 0, 0);
}

#define BAR()  do { asm volatile("" ::: "memory"); __builtin_amdgcn_s_barrier(); asm volatile("" ::: "memory"); } while (0)
#define VMC(N) asm volatile("s_waitcnt vmcnt(" #N ")" ::: "memory")

// ---------------------------------------------------------------------------
// Conversion kernels: f32 -> bf16 (A linear, B transposed so GEMM sees B^T)
// ---------------------------------------------------------------------------
__global__ void conv_a(const float* __restrict__ a, unsigned short* __restrict__ out) {
    size_t idx = (size_t)blockIdx.x * blockDim.x + threadIdx.x;
    float4 v = ((const float4*)a)[idx];
    ushort4 o;
    o.x = f2bf_rne(v.x); o.y = f2bf_rne(v.y); o.z = f2bf_rne(v.z); o.w = f2bf_rne(v.w);
    ((ushort4*)out)[idx] = o;
}

__global__ void conv_bt(const float* __restrict__ b, unsigned short* __restrict__ bt) {
    __shared__ float tile[64][65];
    const int tn = blockIdx.x, tk = blockIdx.y;
    for (int i = threadIdx.x; i < 64 * 64; i += 256) {
        int r = i >> 6, c = i & 63;
        tile[r][c] = b[(size_t)(tk * 64 + r) * Ndim + tn * 64 + c];
    }
    __syncthreads();
    for (int i = threadIdx.x; i < 64 * 64; i += 256) {
        int n = i >> 6, k = i & 63;
        bt[(size_t)(tn * 64 + n) * Kdim + tk * 64 + k] = f2bf_rne(tile[k][n]);
    }
}

// ---------------------------------------------------------------------------
// 128x256 bf16 GEMM (C = A*B, B given as B^T), cross-phase register pipeline.
// 512 thr = 8 waves (2M x 4N), per-wave 64x64 out -> acc[4][4] = 64 VGPR.
// BK=64, double-buffered LDS = 2 x (B0 16K | B1 16K | A 16K) = 96 KiB.
// LDS regions: B-half h holds B^T rows bn*256 + h*128 + [0,128); A holds
// rows bm*128 + [0,128). Wave (wm,wn) reads A rows wm*64+.., B region wn>>1,
// local rows (wn&1)*64+.. . Swizzle: LDS[p][q] = global[p][q ^ (p&7)] in 16B
// chunks, applied by pre-swizzling the gload source; reads XOR with row&7.
//
// Per 2-tile iter (t=buf0, t+1=buf1), 8 phases; MFMA consumes ONLY reads from
// earlier phases (LDS latency hidden); 2 x vmcnt(4), never 0:
//  ph1: rd bO<-B[t]N1          |           | Q00(aE,bEa) |
//  ph2: rd aO<-A[t]m1          | stg B0[t+2]| Q01(aE,bO) |
//  ph3:                        | stg B1[t+2]| Q11(aO,bO) | VMC(4)
//  ph4: rd aE<-A[t+1]m0,bEb<-B[t+1]N0 | stg A[t+2] | Q10(aO,bEa) |
//  ph5-8: same with buf1, bEa<->bEb, stages t+3, VMC(4) at ph7.
// WAR: each stage >=1 barrier after last read of the region it overwrites.
// RAW: each read preceded by a VMC retiring its stage + an intervening BAR.
// Queue invariant entering ph1: {B0,B1,A}[t+1] = 6 loads (verified induction).
// ---------------------------------------------------------------------------
__global__ __launch_bounds__(512, 2) void gemm_rp(const unsigned short* __restrict__ A,
                                                  const unsigned short* __restrict__ Bt,
                                                  float* __restrict__ C) {
    __shared__ unsigned short lds[49152];  // 96 KiB

    const int tid  = threadIdx.x;
    const int lane = tid & 63;
    const int w    = tid >> 6;   // 0..7
    const int wm   = w >> 2;     // 0..1
    const int wn   = w & 3;      // 0..3

    // bijective XCD swizzle (gridDim.x = 512, 512 % 8 == 0)
    const int nch = gridDim.x >> 3;
    const int swz = (blockIdx.x & 7) * nch + (blockIdx.x >> 3);
    const int bm  = swz >> 4;    // 0..31
    const int bn  = swz & 15;    // 0..15

    // ---- staging: per region 16KB = 8 waves x 2 instr x 1KB ----
    const int prow = w * 8 + (lane >> 3);              // packed row (j=0)
    const int c0   = ((lane & 7) ^ (lane >> 3)) * 8;   // pre-swizzled chunk (elems)

    const unsigned short* gA0  = A  + ((size_t)(bm * 128 + prow) << 12) + c0;
    const unsigned short* gA1  = gA0 + ((size_t)64 << 12);
    const unsigned short* gB00 = Bt + ((size_t)(bn * 256 + prow) << 12) + c0;
    const unsigned short* gB01 = gB00 + ((size_t)64 << 12);
    const unsigned short* gB10 = gB00 + ((size_t)128 << 12);
    const unsigned short* gB11 = gB00 + ((size_t)192 << 12);

    unsigned short* sB = lds + w * 512;  // wave's j=0 slot (shorts)

    // region offsets in shorts: buf*24576 + {B0:0, B1:8192, A:16384}
#define STG_B0(BUF) do { gload_lds16(gB00, sB + (BUF) * 24576);                 \
                         gload_lds16(gB01, sB + (BUF) * 24576 + 4096); } while (0)
#define STG_B1(BUF) do { gload_lds16(gB10, sB + (BUF) * 24576 + 8192);          \
                         gload_lds16(gB11, sB + (BUF) * 24576 + 12288); } while (0)
#define STG_A(BUF)  do { gload_lds16(gA0,  sB + (BUF) * 24576 + 16384);         \
                         gload_lds16(gA1,  sB + (BUF) * 24576 + 20480); } while (0)
#define ADV() do { gA0 += 64; gA1 += 64; gB00 += 64; gB01 += 64;                \
                   gB10 += 64; gB11 += 64; } while (0)

    // ---- fragment read addressing (byte offsets into lds) ----
    const int fr = lane & 15;
    const int hi = lane >> 4;
    const int sx = fr & 7;
    const char* ldsc = (const char*)lds;

    const int ck0 = ((0 * 4 + hi) ^ sx) << 4;   // kk=0 swizzled chunk
    const int ck1 = ((1 * 4 + hi) ^ sx) << 4;   // kk=1

    const int adA00 = 0 * 49152 + 32768 + (wm * 64 + fr) * 128 + ck0;
    const int adA01 = 0 * 49152 + 32768 + (wm * 64 + fr) * 128 + ck1;
    const int adA10 = 1 * 49152 + 32768 + (wm * 64 + fr) * 128 + ck0;
    const int adA11 = 1 * 49152 + 32768 + (wm * 64 + fr) * 128 + ck1;
    const int brow  = (wn >> 1) * 16384 + ((wn & 1) * 64 + fr) * 128;
    const int adB00 = 0 * 49152 + brow + ck0;
    const int adB01 = 0 * 49152 + brow + ck1;
    const int adB10 = 1 * 49152 + brow + ck0;
    const int adB11 = 1 * 49152 + brow + ck1;

#define LDA_Q(DST, B, MH) do {                                                  \
        DST[0][0] = *(const bf16x8*)(ldsc + adA##B##0 + (2 * (MH) + 0) * 2048); \
        DST[0][1] = *(const bf16x8*)(ldsc + adA##B##1 + (2 * (MH) + 0) * 2048); \
        DST[1][0] = *(const bf16x8*)(ldsc + adA##B##0 + (2 * (MH) + 1) * 2048); \
        DST[1][1] = *(const bf16x8*)(ldsc + adA##B##1 + (2 * (MH) + 1) * 2048); \
    } while (0)
#define LDB_Q(DST, B, NH) do {                                                  \
        DST[0][0] = *(const bf16x8*)(ldsc + adB##B##0 + (2 * (NH) + 0) * 2048); \
        DST[0][1] = *(const bf16x8*)(ldsc + adB##B##1 + (2 * (NH) + 0) * 2048); \
        DST[1][0] = *(const bf16x8*)(ldsc + adB##B##0 + (2 * (NH) + 1) * 2048); \
        DST[1][1] = *(const bf16x8*)(ldsc + adB##B##1 + (2 * (NH) + 1) * 2048); \
    } while (0)

#define MMA_Q(MH, NH, AF, BF) do {                                              \
        __builtin_amdgcn_s_setprio(1);                                          \
        _Pragma("unroll")                                                       \
        for (int mi = 0; mi < 2; ++mi)                                          \
            _Pragma("unroll")                                                   \
            for (int ni = 0; ni < 2; ++ni) {                                    \
                acc[2*(MH)+mi][2*(NH)+ni] = __builtin_amdgcn_mfma_f32_16x16x32_bf16( \
                    AF[mi][0], BF[ni][0], acc[2*(MH)+mi][2*(NH)+ni], 0, 0, 0);  \
                acc[2*(MH)+mi][2*(NH)+ni] = __builtin_amdgcn_mfma_f32_16x16x32_bf16( \
                    AF[mi][1], BF[ni][1], acc[2*(MH)+mi][2*(NH)+ni], 0, 0, 0);  \
            }                                                                   \
        __builtin_amdgcn_s_setprio(0);                                          \
    } while (0)

    f32x4 acc[4][4] = {};
    bf16x8 aE[2][2], aO[2][2], bO[2][2], bEa[2][2], bEb[2][2];

    // ---- prologue: stage tiles 0,1; retire tile 0; pre-read aE, bEa ----
    STG_B0(0); STG_B1(0); STG_A(0); ADV();
    STG_B0(1); STG_B1(1); STG_A(1); ADV();
    VMC(6);                       // retire tile 0 (oldest 6 loads)
    BAR();
    LDA_Q(aE, 0, 0);              // A[0] mh0
    LDB_Q(bEa, 0, 0);             // B[0] nh0

    // ---- main loop: tiles (t, t+1), t = 0..60 step 2; stages t+2, t+3 ----
    for (int i = 0; i < 31; ++i) {
        // ph1
        LDB_Q(bO, 0, 1);
        BAR();
        MMA_Q(0, 0, aE, bEa);
        BAR();
        // ph2
        LDA_Q(aO, 0, 1);
        STG_B0(0);
        BAR();
        MMA_Q(0, 1, aE, bO);
        BAR();
        // ph3
        STG_B1(0);
        BAR();
        MMA_Q(1, 1, aO, bO);
        VMC(4);                   // retire {B0,B1,A}[t+1]
        BAR();
        // ph4
        LDA_Q(aE, 1, 0);
        LDB_Q(bEb, 1, 0);
        STG_A(0);
        BAR();
        MMA_Q(1, 0, aO, bEa);
        BAR();
        ADV();
        // ph5
        LDB_Q(bO, 1, 1);
        BAR();
        MMA_Q(0, 0, aE, bEb);
        BAR();
        // ph6
        LDA_Q(aO, 1, 1);
        STG_B0(1);
        BAR();
        MMA_Q(0, 1, aE, bO);
        BAR();
        // ph7
        STG_B1(1);
        BAR();
        MMA_Q(1, 1, aO, bO);
        VMC(4);                   // retire {B0,B1,A}[t+2]
        BAR();
        // ph8
        LDA_Q(aE, 0, 0);
        LDB_Q(bEa, 0, 0);
        STG_A(1);
        BAR();
        MMA_Q(1, 0, aO, bEb);
        BAR();
        ADV();
    }

    // ---- epilogue: tiles 62 (buf0), 63 (buf1); no stages, drain once ----
    VMC(0);
    BAR();
    LDB_Q(bO, 0, 1);
    MMA_Q(0, 0, aE, bEa);
    LDA_Q(aO, 0, 1);
    MMA_Q(0, 1, aE, bO);
    MMA_Q(1, 1, aO, bO);
    LDA_Q(aE, 1, 0);
    LDB_Q(bEb, 1, 0);
    MMA_Q(1, 0, aO, bEa);
    LDB_Q(bO, 1, 1);
    MMA_Q(0, 0, aE, bEb);
    LDA_Q(aO, 1, 1);
    MMA_Q(0, 1, aE, bO);
    MMA_Q(1, 1, aO, bO);
    MMA_Q(1, 0, aO, bEb);

    // ---- C write: row = (lane>>4)*4 + reg, col = lane&15 per 16x16 frag ----
    const size_t crow = (size_t)(bm * 128 + wm * 64 + hi * 4);
    const int    ccol = bn * 256 + wn * 64 + fr;
#pragma unroll
    for (int mi = 0; mi < 4; ++mi)
#pragma unroll
        for (int ni = 0; ni < 4; ++ni) {
            const size_t row = crow + mi * 16;
            const int    col = ccol + ni * 16;
#pragma unroll
            for (int r = 0; r < 4; ++r)
                C[(row + r) * Ndim + col] = acc[mi][ni][r];
        }

#undef STG_B0
#undef STG_B1
#undef STG_A
#undef ADV
#undef LDA_Q
#undef LDB_Q
#undef MMA_Q
}

// ---------------------------------------------------------------------------
// Fallback if workspace too small: plain f32 tiles
// ---------------------------------------------------------------------------
__global__ void gemm_f32_naive(const float* __restrict__ A, const float* __restrict__ B,
                               float* __restrict__ C) {
    __shared__ float As[32][33], Bs[32][33];
    const int tx = threadIdx.x & 31, ty = threadIdx.x >> 5;
    const int row0 = blockIdx.y * 32, col0 = blockIdx.x * 32;
    float acc[4] = {0.f, 0.f, 0.f, 0.f};
    for (int k0 = 0; k0 < Kdim; k0 += 32) {
        for (int i = threadIdx.x; i < 32 * 32; i += 256) {
            int r = i >> 5, c = i & 31;
            As[r][c] = A[(size_t)(row0 + r) * Kdim + k0 + c];
            Bs[r][c] = B[(size_t)(k0 + r) * Ndim + col0 + c];
        }
        __syncthreads();
#pragma unroll 8
        for (int kk = 0; kk < 32; ++kk) {
            float bv = Bs[kk][tx];
#pragma unroll
            for (int i = 0; i < 4; ++i) acc[i] += As[ty + 8 * i][kk] * bv;
        }
        __syncthreads();
    }
#pragma unroll
    for (int i = 0; i < 4; ++i)
        C[(size_t)(row0 + ty + 8 * i) * Ndim + col0 + tx] = acc[i];
}

extern "C" void kernel_launch(void* const* d_in, const int* in_sizes, int n_in,
                              void* d_out, int out_size, void* d_ws, size_t ws_size,
                              hipStream_t stream) {
    const float* x = (const float*)d_in[0];
    const float* y = (const float*)d_in[1];
    float* out = (float*)d_out;

    const size_t elemsA = (size_t)Mdim * Kdim;
    const size_t elemsB = (size_t)Ndim * Kdim;
    const size_t need   = (elemsA + elemsB) * sizeof(unsigned short);  // 64 MiB

    if (ws_size >= need) {
        unsigned short* Abf = (unsigned short*)d_ws;
        unsigned short* Btb = Abf + elemsA;

        conv_a<<<(unsigned)(elemsA / 4 / 256), 256, 0, stream>>>(x, Abf);
        conv_bt<<<dim3(Ndim / 64, Kdim / 64), 256, 0, stream>>>(y, Btb);
        gemm_rp<<<dim3((Mdim / 128) * (Ndim / 256)), 512, 0, stream>>>(Abf, Btb, out);
    } else {
        gemm_f32_naive<<<dim3(Ndim / 32, Mdim / 32), 256, 0, stream>>>(x, y, out);
    }
}

// Round 5
// 163.048 us; speedup vs baseline: 1.5741x; 1.0301x over previous
//
#include <hip/hip_runtime.h>
#include <stdint.h>

#define Mdim 4096
#define Kdim 4096
#define Ndim 4096

typedef __attribute__((ext_vector_type(8))) short bf16x8;    // 8 bf16 (MFMA A/B frag)
typedef __attribute__((ext_vector_type(16))) float f32x16;   // 32x32 MFMA C/D frag

static __device__ __forceinline__ unsigned short f2bf_rne(float f) {
    union { float f; unsigned u; } v; v.f = f;
    unsigned u = v.u;
    u += 0x7FFFu + ((u >> 16) & 1u);
    return (unsigned short)(u >> 16);
}

static __device__ __forceinline__ void gload_lds16(const unsigned short* g, unsigned short* l) {
    __builtin_amdgcn_global_load_lds(
        (const __attribute__((address_space(1))) unsigned int*)g,
        (__attribute__((address_space(3))) unsigned int*)l,
        16, 0, 0);
}

#define BAR()  do { asm volatile("" ::: "memory"); __builtin_amdgcn_s_barrier(); asm volatile("" ::: "memory"); } while (0)
#define VMC(N) asm volatile("s_waitcnt vmcnt(" #N ")" ::: "memory")
#define SB()   __builtin_amdgcn_sched_barrier(0)

// ---------------------------------------------------------------------------
// Conversion kernels: f32 -> bf16 (A linear, B transposed so GEMM sees B^T)
// ---------------------------------------------------------------------------
__global__ void conv_a(const float* __restrict__ a, unsigned short* __restrict__ out) {
    size_t idx = (size_t)blockIdx.x * blockDim.x + threadIdx.x;
    float4 v = ((const float4*)a)[idx];
    ushort4 o;
    o.x = f2bf_rne(v.x); o.y = f2bf_rne(v.y); o.z = f2bf_rne(v.z); o.w = f2bf_rne(v.w);
    ((ushort4*)out)[idx] = o;
}

__global__ void conv_bt(const float* __restrict__ b, unsigned short* __restrict__ bt) {
    __shared__ float tile[64][65];
    const int tn = blockIdx.x, tk = blockIdx.y;
    for (int i = threadIdx.x; i < 64 * 64; i += 256) {
        int r = i >> 6, c = i & 63;
        tile[r][c] = b[(size_t)(tk * 64 + r) * Ndim + tn * 64 + c];
    }
    __syncthreads();
    for (int i = threadIdx.x; i < 64 * 64; i += 256) {
        int n = i >> 6, k = i & 63;
        bt[(size_t)(tn * 64 + n) * Kdim + tk * 64 + k] = f2bf_rne(tile[k][n]);
    }
}

// ---------------------------------------------------------------------------
// 256x256 bf16 GEMM (C = A*B, B as B^T), 32x32x16 MFMA, register-pipelined
// windows, 2 barriers per K-tile.
// 512 thr = 8 waves (2M x 4N); per-wave 128x64 out = 4x2 f32x16 acc (128 AGPR).
// BK=64 -> 4 k-steps (ks) of 16. LDS: buf(2) x [A 32KB | B 32KB] = 128 KiB.
// Swizzle: stored chunk c of row r holds logical chunk c^(r&7) (16B chunks);
// applied by pre-swizzling the gload SOURCE column; reads XOR with row&7.
//
// Per K-tile t (buf P, next Q), 4 windows:
//   w0: [stage 8 loads for t+1 -> Q] [rd ks1->O] [8 MFMA ks0 (E)] SB
//   w1:                              [rd ks2->E] [8 MFMA ks1 (O)] SB
//   w2:                              [rd ks3->O] [8 MFMA ks2 (E)] SB
//   w3: VMC(0) BAR [rd ks0(t+1) from Q ->E] [8 MFMA ks3 (O)] SB BAR
// Reads consumed one window later (compiler emits counted lgkmcnt(6)) ->
// LDS drain (576 cyc/window blockwide) overlaps MFMA (516 cyc).
// WAR: stages(t+1)->Q issue after end-BAR of t-1 (all Q reads of t-1 lgkm'd
// before their ks3 MFMA, which precedes that BAR). RAW: VMC(0)+BAR before
// first Q read. sched_barrier(0) pins windows against compiler sinking.
// ---------------------------------------------------------------------------
__global__ __launch_bounds__(512, 2) void gemm32(const unsigned short* __restrict__ A,
                                                 const unsigned short* __restrict__ Bt,
                                                 float* __restrict__ C) {
    __shared__ unsigned short lds[65536];  // 128 KiB

    const int lane = threadIdx.x & 63;
    const int w    = threadIdx.x >> 6;   // 0..7
    const int wm   = w >> 2;             // 0..1
    const int wn   = w & 3;              // 0..3
    const int ln31 = lane & 31;
    const int hb   = lane >> 5;

    // bijective XCD swizzle (gridDim.x = 256)
    const int nch = gridDim.x >> 3;
    const int swz = (blockIdx.x & 7) * nch + (blockIdx.x >> 3);
    const int bm  = swz >> 4;
    const int bn  = swz & 15;

    // ---- stage pointers: instr j covers rows 64j+8w+(lane>>3), chunk (lane&7)^(lane>>3) ----
    const int schk = ((lane & 7) ^ (lane >> 3)) * 8;   // pre-swizzled source elems
    const int srow = 8 * w + (lane >> 3);
    const unsigned short* gA0 = A  + ((size_t)(bm * 256 +   0 + srow) << 12) + schk;
    const unsigned short* gA1 = A  + ((size_t)(bm * 256 +  64 + srow) << 12) + schk;
    const unsigned short* gA2 = A  + ((size_t)(bm * 256 + 128 + srow) << 12) + schk;
    const unsigned short* gA3 = A  + ((size_t)(bm * 256 + 192 + srow) << 12) + schk;
    const unsigned short* gB0 = Bt + ((size_t)(bn * 256 +   0 + srow) << 12) + schk;
    const unsigned short* gB1 = Bt + ((size_t)(bn * 256 +  64 + srow) << 12) + schk;
    const unsigned short* gB2 = Bt + ((size_t)(bn * 256 + 128 + srow) << 12) + schk;
    const unsigned short* gB3 = Bt + ((size_t)(bn * 256 + 192 + srow) << 12) + schk;

    // LDS dest (shorts): buf*32768 + mat*16384 + (j*8+w)*512 (+ lane*16B by HW)
#define STAGE_ALL(Q) do {                                                   \
        unsigned short* d = lds + (Q) * 32768 + w * 512;                    \
        gload_lds16(gA0, d);            gload_lds16(gA1, d + 4096);         \
        gload_lds16(gA2, d + 8192);     gload_lds16(gA3, d + 12288);        \
        gload_lds16(gB0, d + 16384);    gload_lds16(gB1, d + 20480);        \
        gload_lds16(gB2, d + 24576);    gload_lds16(gB3, d + 28672);        \
    } while (0)
#define ADV() do { gA0 += 64; gA1 += 64; gA2 += 64; gA3 += 64;              \
                   gB0 += 64; gB1 += 64; gB2 += 64; gB3 += 64; } while (0)

    // ---- fragment read addresses (byte offsets), 16 precomputed bases ----
    const char* ldsc = (const char*)lds;
    int vaA[2][4], vaB[2][4];
#pragma unroll
    for (int b = 0; b < 2; ++b)
#pragma unroll
        for (int ks = 0; ks < 4; ++ks) {
            const int ck = ((ks * 2 + hb) ^ (ln31 & 7)) << 4;
            vaA[b][ks] = b * 65536 +         (wm * 128 + ln31) * 128 + ck;
            vaB[b][ks] = b * 65536 + 32768 + (wn *  64 + ln31) * 128 + ck;
        }

#define READ_A(DST, B, KS) do {                                             \
        DST[0] = *(const bf16x8*)(ldsc + vaA[B][KS]);                       \
        DST[1] = *(const bf16x8*)(ldsc + vaA[B][KS] + 4096);                \
        DST[2] = *(const bf16x8*)(ldsc + vaA[B][KS] + 8192);                \
        DST[3] = *(const bf16x8*)(ldsc + vaA[B][KS] + 12288);               \
    } while (0)
#define READ_B(DST, B, KS) do {                                             \
        DST[0] = *(const bf16x8*)(ldsc + vaB[B][KS]);                       \
        DST[1] = *(const bf16x8*)(ldsc + vaB[B][KS] + 4096);                \
    } while (0)

#define MFMA_ALL(AF, BF) do {                                               \
        __builtin_amdgcn_s_setprio(1);                                      \
        _Pragma("unroll")                                                   \
        for (int mi = 0; mi < 4; ++mi)                                      \
            _Pragma("unroll")                                               \
            for (int nj = 0; nj < 2; ++nj)                                  \
                acc[mi][nj] = __builtin_amdgcn_mfma_f32_32x32x16_bf16(      \
                    AF[mi], BF[nj], acc[mi][nj], 0, 0, 0);                  \
        __builtin_amdgcn_s_setprio(0);                                      \
    } while (0)

// One K-tile: P = this tile's buf, Q = other buf.
#define TILE(P, Q, DO_STG, DO_NXT, DO_SYNC) do {                            \
        if (DO_STG) STAGE_ALL(Q);                                           \
        READ_A(aO, P, 1); READ_B(bO, P, 1);                                 \
        MFMA_ALL(aE, bE); SB();                                             \
        READ_A(aE, P, 2); READ_B(bE, P, 2);                                 \
        MFMA_ALL(aO, bO); SB();                                             \
        READ_A(aO, P, 3); READ_B(bO, P, 3);                                 \
        MFMA_ALL(aE, bE); SB();                                             \
        if (DO_SYNC) { VMC(0); BAR(); }                                     \
        if (DO_NXT) { READ_A(aE, Q, 0); READ_B(bE, Q, 0); }                 \
        MFMA_ALL(aO, bO); SB();                                             \
        BAR();                                                              \
        if (DO_STG) ADV();                                                  \
    } while (0)

    f32x16 acc[4][2] = {};
    bf16x8 aE[4], aO[4], bE[2], bO[2];

    // ---- prologue: stage tile 0, retire, read ks0 into E ----
    STAGE_ALL(0); ADV();
    VMC(0); BAR();
    READ_A(aE, 0, 0); READ_B(bE, 0, 0);

    // ---- tiles 0..61 (each stages t+1), then 62 (stages 63), then 63 ----
    for (int i = 0; i < 31; ++i) {
        TILE(0, 1, 1, 1, 1);
        TILE(1, 0, 1, 1, 1);
    }
    TILE(0, 1, 1, 1, 1);   // tile 62
    TILE(1, 0, 0, 0, 0);   // tile 63

    // ---- C write: 32x32 C/D layout col=lane&31, row=(r&3)+8*(r>>2)+4*hb ----
    const size_t crow = (size_t)(bm * 256 + wm * 128 + 4 * hb);
    const int    ccol = bn * 256 + wn * 64 + ln31;
#pragma unroll
    for (int mi = 0; mi < 4; ++mi)
#pragma unroll
        for (int nj = 0; nj < 2; ++nj) {
            const size_t rb = crow + mi * 32;
            const int    cb = ccol + nj * 32;
#pragma unroll
            for (int r = 0; r < 16; ++r) {
                const size_t row = rb + (r & 3) + 8 * (r >> 2);
                C[row * Ndim + cb] = acc[mi][nj][r];
            }
        }

#undef STAGE_ALL
#undef ADV
#undef READ_A
#undef READ_B
#undef MFMA_ALL
#undef TILE
}

// ---------------------------------------------------------------------------
// Fallback if workspace too small: plain f32 tiles
// ---------------------------------------------------------------------------
__global__ void gemm_f32_naive(const float* __restrict__ A, const float* __restrict__ B,
                               float* __restrict__ C) {
    __shared__ float As[32][33], Bs[32][33];
    const int tx = threadIdx.x & 31, ty = threadIdx.x >> 5;
    const int row0 = blockIdx.y * 32, col0 = blockIdx.x * 32;
    float acc[4] = {0.f, 0.f, 0.f, 0.f};
    for (int k0 = 0; k0 < Kdim; k0 += 32) {
        for (int i = threadIdx.x; i < 32 * 32; i += 256) {
            int r = i >> 5, c = i & 31;
            As[r][c] = A[(size_t)(row0 + r) * Kdim + k0 + c];
            Bs[r][c] = B[(size_t)(k0 + r) * Ndim + col0 + c];
        }
        __syncthreads();
#pragma unroll 8
        for (int kk = 0; kk < 32; ++kk) {
            float bv = Bs[kk][tx];
#pragma unroll
            for (int i = 0; i < 4; ++i) acc[i] += As[ty + 8 * i][kk] * bv;
        }
        __syncthreads();
    }
#pragma unroll
    for (int i = 0; i < 4; ++i)
        C[(size_t)(row0 + ty + 8 * i) * Ndim + col0 + tx] = acc[i];
}

extern "C" void kernel_launch(void* const* d_in, const int* in_sizes, int n_in,
                              void* d_out, int out_size, void* d_ws, size_t ws_size,
                              hipStream_t stream) {
    const float* x = (const float*)d_in[0];
    const float* y = (const float*)d_in[1];
    float* out = (float*)d_out;

    const size_t elemsA = (size_t)Mdim * Kdim;
    const size_t elemsB = (size_t)Ndim * Kdim;
    const size_t need   = (elemsA + elemsB) * sizeof(unsigned short);  // 64 MiB

    if (ws_size >= need) {
        unsigned short* Abf = (unsigned short*)d_ws;
        unsigned short* Btb = Abf + elemsA;

        conv_a<<<(unsigned)(elemsA / 4 / 256), 256, 0, stream>>>(x, Abf);
        conv_bt<<<dim3(Ndim / 64, Kdim / 64), 256, 0, stream>>>(y, Btb);
        gemm32<<<dim3((Mdim / 256) * (Ndim / 256)), 512, 0, stream>>>(Abf, Btb, out);
    } else {
        gemm_f32_naive<<<dim3(Ndim / 32, Mdim / 32), 256, 0, stream>>>(x, y, out);
    }
}

// Round 6
// 149.126 us; speedup vs baseline: 1.7211x; 1.0934x over previous
//
#include <hip/hip_runtime.h>
#include <stdint.h>

#define Mdim 4096
#define Kdim 4096
#define Ndim 4096

typedef __attribute__((ext_vector_type(8))) short bf16x8;   // 8 bf16 (MFMA A/B frag)
typedef __attribute__((ext_vector_type(4))) float f32x4;    // 16x16 MFMA C/D frag

static __device__ __forceinline__ unsigned short f2bf_rne(float f) {
    union { float f; unsigned u; } v; v.f = f;
    unsigned u = v.u;
    u += 0x7FFFu + ((u >> 16) & 1u);
    return (unsigned short)(u >> 16);
}

static __device__ __forceinline__ void gload_lds16(const unsigned short* g, unsigned short* l) {
    __builtin_amdgcn_global_load_lds(
        (const __attribute__((address_space(1))) unsigned int*)g,
        (__attribute__((address_space(3))) unsigned int*)l,
        16, 0, 0);
}

#define BAR()  do { asm volatile("" ::: "memory"); __builtin_amdgcn_s_barrier(); asm volatile("" ::: "memory"); } while (0)
#define VMC(N) asm volatile("s_waitcnt vmcnt(" #N ")" ::: "memory")
#define SB()   __builtin_amdgcn_sched_barrier(0)

// ---------------------------------------------------------------------------
// Conversion kernels: f32 -> bf16 (A linear, B transposed so GEMM sees B^T)
// ---------------------------------------------------------------------------
__global__ void conv_a(const float* __restrict__ a, unsigned short* __restrict__ out) {
    size_t idx = (size_t)blockIdx.x * blockDim.x + threadIdx.x;
    float4 v = ((const float4*)a)[idx];
    ushort4 o;
    o.x = f2bf_rne(v.x); o.y = f2bf_rne(v.y); o.z = f2bf_rne(v.z); o.w = f2bf_rne(v.w);
    ((ushort4*)out)[idx] = o;
}

__global__ void conv_bt(const float* __restrict__ b, unsigned short* __restrict__ bt) {
    __shared__ float tile[64][65];
    const int tn = blockIdx.x, tk = blockIdx.y;
    for (int i = threadIdx.x; i < 64 * 64; i += 256) {
        int r = i >> 6, c = i & 63;
        tile[r][c] = b[(size_t)(tk * 64 + r) * Ndim + tn * 64 + c];
    }
    __syncthreads();
    for (int i = threadIdx.x; i < 64 * 64; i += 256) {
        int n = i >> 6, k = i & 63;
        bt[(size_t)(tn * 64 + n) * Kdim + tk * 64 + k] = f2bf_rne(tile[k][n]);
    }
}

// ---------------------------------------------------------------------------
// 256x256 bf16 GEMM (C = A*B, B as B^T), 16x16x32 MFMA, 4 register-pipelined
// windows per K-tile, 2 barriers per tile.
// 512 thr = 8 waves (2M x 4N); per-wave 128x64 out = acc[8][4] f32x4 (128 reg).
// BK=64 -> kk in {0,1} (k-chunks of 32). LDS: buf(2) x [A 32KB | B 32KB].
// Swizzle: stored 16B-chunk c of row r holds logical chunk c^(r&7); applied by
// pre-swizzling the gload SOURCE; fragment reads XOR the chunk with fr&7.
// 16-lane row groups x 4 hi k-chunks => 2 lanes/chunk = conflict-free (round-2
// verified zero-conflict pattern; 32x32 shape is fundamentally 4-way here).
//
// Per K-tile t (buf P, other Q):
//  w0: [stage 8 loads t+1->Q] [rdA(P,kk0,mh1)->aO]            [16 MFMA mh0,kk0(aE,bE)] SB
//  w1: [rdA(P,kk1,mh0)->aE; rdB(P,kk1)->bO]                   [16 MFMA mh1,kk0(aO,bE)] SB
//  w2: [rdA(P,kk1,mh1)->aO]                                   [16 MFMA mh0,kk1(aE,bO)] SB
//  w3: VMC(0) BAR [rdA(Q,kk0,mh0)->aE; rdB(Q,kk0)->bE]        [16 MFMA mh1,kk1(aO,bO)] SB BAR
// Every MFMA consumes only prior-window reads (compiler emits counted lgkmcnt
// -> LDS drain overlaps MFMA). VMC(0) at w3 retires exactly the 8 stage loads
// issued at w0 (~3 windows ≈ 1800 cyc > 900 cyc HBM latency). WAR: all reads
// of buf Q complete by tile t-1's w3-MFMA lgkm wait (in-order), before the
// end-BAR that precedes stage->Q. sched_barrier(0) pins windows vs sinking.
// ---------------------------------------------------------------------------
__global__ __launch_bounds__(512, 2) void gemm16w(const unsigned short* __restrict__ A,
                                                  const unsigned short* __restrict__ Bt,
                                                  float* __restrict__ C) {
    __shared__ unsigned short lds[65536];  // 128 KiB

    const int lane = threadIdx.x & 63;
    const int w    = threadIdx.x >> 6;   // 0..7
    const int wm   = w >> 2;             // 0..1
    const int wn   = w & 3;              // 0..3

    // bijective XCD swizzle (gridDim.x = 256)
    const int nch = gridDim.x >> 3;
    const int swz = (blockIdx.x & 7) * nch + (blockIdx.x >> 3);
    const int bm  = swz >> 4;
    const int bn  = swz & 15;

    // ---- staging: instr j covers rows 64j + 8w + (lane>>3), pre-swizzled chunk ----
    const int schk = ((lane & 7) ^ (lane >> 3)) * 8;   // source elems
    const int srow = 8 * w + (lane >> 3);
    const unsigned short* gA0 = A  + ((size_t)(bm * 256 +   0 + srow) << 12) + schk;
    const unsigned short* gA1 = A  + ((size_t)(bm * 256 +  64 + srow) << 12) + schk;
    const unsigned short* gA2 = A  + ((size_t)(bm * 256 + 128 + srow) << 12) + schk;
    const unsigned short* gA3 = A  + ((size_t)(bm * 256 + 192 + srow) << 12) + schk;
    const unsigned short* gB0 = Bt + ((size_t)(bn * 256 +   0 + srow) << 12) + schk;
    const unsigned short* gB1 = Bt + ((size_t)(bn * 256 +  64 + srow) << 12) + schk;
    const unsigned short* gB2 = Bt + ((size_t)(bn * 256 + 128 + srow) << 12) + schk;
    const unsigned short* gB3 = Bt + ((size_t)(bn * 256 + 192 + srow) << 12) + schk;

#define STAGE_ALL(Q) do {                                                   \
        unsigned short* d = lds + (Q) * 32768 + w * 512;                    \
        gload_lds16(gA0, d);            gload_lds16(gA1, d + 4096);         \
        gload_lds16(gA2, d + 8192);     gload_lds16(gA3, d + 12288);        \
        gload_lds16(gB0, d + 16384);    gload_lds16(gB1, d + 20480);        \
        gload_lds16(gB2, d + 24576);    gload_lds16(gB3, d + 28672);        \
    } while (0)
#define ADV() do { gA0 += 64; gA1 += 64; gA2 += 64; gA3 += 64;              \
                   gB0 += 64; gB1 += 64; gB2 += 64; gB3 += 64; } while (0)

    // ---- fragment read addressing (round-2 conflict-free pattern) ----
    const int fr = lane & 15;
    const int hi = lane >> 4;
    const int sx = fr & 7;
    const char* ldsc = (const char*)lds;

    const int ckE = ((0 * 4 + hi) ^ sx) << 4;   // kk0 swizzled chunk (bytes)
    const int ckO = ((1 * 4 + hi) ^ sx) << 4;   // kk1

    const int adA0 = 0 * 65536 +         (wm * 128 + fr) * 128;
    const int adA1 = 1 * 65536 +         (wm * 128 + fr) * 128;
    const int adB0 = 0 * 65536 + 32768 + (wn *  64 + fr) * 128;
    const int adB1 = 1 * 65536 + 32768 + (wn *  64 + fr) * 128;

#define RD_A(DST, BUF, CK, MH) do { _Pragma("unroll")                        \
        for (int m_ = 0; m_ < 4; ++m_)                                       \
            DST[m_] = *(const bf16x8*)(ldsc + adA##BUF + (CK) +              \
                                       (MH) * 8192 + m_ * 2048);             \
    } while (0)
#define RD_B(DST, BUF, CK) do { _Pragma("unroll")                            \
        for (int n_ = 0; n_ < 4; ++n_)                                       \
            DST[n_] = *(const bf16x8*)(ldsc + adB##BUF + (CK) + n_ * 2048);  \
    } while (0)

#define MFMA_H(MH, AF, BF) do {                                              \
        __builtin_amdgcn_s_setprio(1);                                       \
        _Pragma("unroll")                                                    \
        for (int m_ = 0; m_ < 4; ++m_)                                       \
            _Pragma("unroll")                                                \
            for (int n_ = 0; n_ < 4; ++n_)                                   \
                acc[(MH) * 4 + m_][n_] = __builtin_amdgcn_mfma_f32_16x16x32_bf16( \
                    AF[m_], BF[n_], acc[(MH) * 4 + m_][n_], 0, 0, 0);        \
        __builtin_amdgcn_s_setprio(0);                                       \
    } while (0)

// One K-tile: P = this tile's buf (0/1 literal), Q = other buf.
#define TILE(P, Q, DO_STG, DO_NXT, DO_SYNC) do {                             \
        if (DO_STG) STAGE_ALL(Q);                                            \
        RD_A(aO, P, ckE, 1);                                                 \
        MFMA_H(0, aE, bE); SB();                                             \
        RD_A(aE, P, ckO, 0); RD_B(bO, P, ckO);                               \
        MFMA_H(1, aO, bE); SB();                                             \
        RD_A(aO, P, ckO, 1);                                                 \
        MFMA_H(0, aE, bO); SB();                                             \
        if (DO_SYNC) { VMC(0); BAR(); }                                      \
        if (DO_NXT) { RD_A(aE, Q, ckE, 0); RD_B(bE, Q, ckE); }               \
        MFMA_H(1, aO, bO); SB();                                             \
        BAR();                                                               \
        if (DO_STG) ADV();                                                   \
    } while (0)

    f32x4 acc[8][4] = {};
    bf16x8 aE[4], aO[4], bE[4], bO[4];

    // ---- prologue: stage tile 0 -> buf0, retire, read kk0/mh0 frags ----
    STAGE_ALL(0); ADV();
    VMC(0); BAR();
    RD_A(aE, 0, ckE, 0); RD_B(bE, 0, ckE);

    // ---- tiles 0..61 (each stages t+1), tile 62 (stages 63), tile 63 ----
    for (int i = 0; i < 31; ++i) {
        TILE(0, 1, 1, 1, 1);
        TILE(1, 0, 1, 1, 1);
    }
    TILE(0, 1, 1, 1, 1);   // tile 62
    TILE(1, 0, 0, 0, 0);   // tile 63

    // ---- C write: 16x16 layout col = lane&15, row = (lane>>4)*4 + reg ----
    const size_t crow = (size_t)(bm * 256 + wm * 128 + hi * 4);
    const int    ccol = bn * 256 + wn * 64 + fr;
#pragma unroll
    for (int mi = 0; mi < 8; ++mi)
#pragma unroll
        for (int ni = 0; ni < 4; ++ni) {
            const size_t row = crow + mi * 16;
            const int    col = ccol + ni * 16;
#pragma unroll
            for (int r = 0; r < 4; ++r)
                C[(row + r) * Ndim + col] = acc[mi][ni][r];
        }

#undef STAGE_ALL
#undef ADV
#undef RD_A
#undef RD_B
#undef MFMA_H
#undef TILE
}

// ---------------------------------------------------------------------------
// Fallback if workspace too small: plain f32 tiles
// ---------------------------------------------------------------------------
__global__ void gemm_f32_naive(const float* __restrict__ A, const float* __restrict__ B,
                               float* __restrict__ C) {
    __shared__ float As[32][33], Bs[32][33];
    const int tx = threadIdx.x & 31, ty = threadIdx.x >> 5;
    const int row0 = blockIdx.y * 32, col0 = blockIdx.x * 32;
    float acc[4] = {0.f, 0.f, 0.f, 0.f};
    for (int k0 = 0; k0 < Kdim; k0 += 32) {
        for (int i = threadIdx.x; i < 32 * 32; i += 256) {
            int r = i >> 5, c = i & 31;
            As[r][c] = A[(size_t)(row0 + r) * Kdim + k0 + c];
            Bs[r][c] = B[(size_t)(k0 + r) * Ndim + col0 + c];
        }
        __syncthreads();
#pragma unroll 8
        for (int kk = 0; kk < 32; ++kk) {
            float bv = Bs[kk][tx];
#pragma unroll
            for (int i = 0; i < 4; ++i) acc[i] += As[ty + 8 * i][kk] * bv;
        }
        __syncthreads();
    }
#pragma unroll
    for (int i = 0; i < 4; ++i)
        C[(size_t)(row0 + ty + 8 * i) * Ndim + col0 + tx] = acc[i];
}

extern "C" void kernel_launch(void* const* d_in, const int* in_sizes, int n_in,
                              void* d_out, int out_size, void* d_ws, size_t ws_size,
                              hipStream_t stream) {
    const float* x = (const float*)d_in[0];
    const float* y = (const float*)d_in[1];
    float* out = (float*)d_out;

    const size_t elemsA = (size_t)Mdim * Kdim;
    const size_t elemsB = (size_t)Ndim * Kdim;
    const size_t need   = (elemsA + elemsB) * sizeof(unsigned short);  // 64 MiB

    if (ws_size >= need) {
        unsigned short* Abf = (unsigned short*)d_ws;
        unsigned short* Btb = Abf + elemsA;

        conv_a<<<(unsigned)(elemsA / 4 / 256), 256, 0, stream>>>(x, Abf);
        conv_bt<<<dim3(Ndim / 64, Kdim / 64), 256, 0, stream>>>(y, Btb);
        gemm16w<<<dim3((Mdim / 256) * (Ndim / 256)), 512, 0, stream>>>(Abf, Btb, out);
    } else {
        gemm_f32_naive<<<dim3(Ndim / 32, Mdim / 32), 256, 0, stream>>>(x, y, out);
    }
}